// Round 18
// baseline (370.748 us; speedup 1.0000x reference)
//
#include <hip/hip_runtime.h>
#include <hip/hip_bf16.h>

#define NBATCH 16
#define SEQ    1024
#define EDIM   1024
#define HDIM   128
#define RSQRT_H 0.08838834764831845f   // 1/sqrt(128)

// R18 = R14 (best, 281.5us) + measurement: an extra idempotent fused_attn launch with
// skip_sweep=1 (replica fan-out disabled, all compute + out0 live). dur - 281.5 isolates
// fused's compute+out0 time. Final state bit-identical to R14.

typedef short s8b  __attribute__((ext_vector_type(8)));
typedef float f32x4 __attribute__((ext_vector_type(4)));
typedef float f4v  __attribute__((ext_vector_type(4)));

__device__ __forceinline__ unsigned short bfr(float f) {   // f32 -> bf16 bits, RNE
    unsigned u = __float_as_uint(f);
    u += 0x7fffu + ((u >> 16) & 1u);
    return (unsigned short)(u >> 16);
}

__device__ __forceinline__ float bf2f(unsigned short h) {  // bf16 bits -> f32
    return __uint_as_float((unsigned)h << 16);
}

__device__ __forceinline__ f32x4 MFMA(s8b a, s8b b, f32x4 c) {
    return __builtin_amdgcn_mfma_f32_16x16x32_bf16(a, b, c, 0, 0, 0);
}

// 4x4 transpose within a quad
__device__ __forceinline__ void quad_transpose(int d, const float y[4], float z[4]) {
    float s0 = (d & 1) ? y[0] : y[1];
    float g0 = __shfl_xor(s0, 1);
    float s1 = (d & 1) ? y[2] : y[3];
    float g1 = __shfl_xor(s1, 1);
    float B0 = (d & 1) ? g0 : y[0];
    float B1 = (d & 1) ? y[1] : g0;
    float B2 = (d & 1) ? g1 : y[2];
    float B3 = (d & 1) ? y[3] : g1;
    float s2 = (d & 2) ? B0 : B2;
    float h0 = __shfl_xor(s2, 2);
    float s3 = (d & 2) ? B1 : B3;
    float h1 = __shfl_xor(s3, 2);
    z[0] = (d & 2) ? h0 : B0;
    z[1] = (d & 2) ? h1 : B1;
    z[2] = (d & 2) ? B2 : h0;
    z[3] = (d & 2) ? B3 : h1;
}

// ---------- prep: weff fold + w_kx/w_qx transposes, one dispatch ----------
__global__ __launch_bounds__(256) void prep_kernel(const float* __restrict__ w_kx,
                                                   const float* __restrict__ w_qx,
                                                   const float* __restrict__ proj_w,
                                                   unsigned short* __restrict__ wkT,
                                                   unsigned short* __restrict__ wqT,
                                                   unsigned short* __restrict__ weffb) {
    __shared__ unsigned short tile[32][40];
    const int blk = blockIdx.x;
    const int t = threadIdx.x;
    if (blk < 2048) {
        const int idx = blk & 1023;
        const float* src = (blk < 1024) ? w_kx : w_qx;
        unsigned short* dst = (blk < 1024) ? wkT : wqT;
        const int e0 = (idx & 31) * 32, h0 = ((idx >> 5) & 3) * 32, hd = idx >> 7;
        const int r = t >> 3, c = (t & 7) * 4;
        float4 v = *(const float4*)(src + ((size_t)hd * 1024 + e0 + r) * 128 + h0 + c);
        tile[r][c]     = bfr(v.x);
        tile[r][c + 1] = bfr(v.y);
        tile[r][c + 2] = bfr(v.z);
        tile[r][c + 3] = bfr(v.w);
        __syncthreads();
        ushort4 o;
        o.x = tile[c][r]; o.y = tile[c + 1][r]; o.z = tile[c + 2][r]; o.w = tile[c + 3][r];
        *(ushort4*)(dst + ((size_t)hd * 128 + h0 + r) * 1024 + e0 + c) = o;
    } else {
        int i = (blk - 2048) * 256 + t;          // 0..131071
        int e = i >> 7, h = i & 127;
        const float* p = proj_w + (size_t)e * (8 * HDIM) + h;
        float s = 0.f;
#pragma unroll
        for (int j = 0; j < 8; ++j) s += p[j * HDIM];
        weffb[i] = bfr(s);
    }
}

// ---------- projx: both k and q; k also writes kxT directly ----------
__global__ __launch_bounds__(256) void projx_mfma(const float* __restrict__ K,
                                                  const float* __restrict__ Q,
                                                  const unsigned short* __restrict__ wkT,
                                                  const unsigned short* __restrict__ wqT,
                                                  unsigned short* __restrict__ kxh,
                                                  unsigned short* __restrict__ qxh,
                                                  unsigned short* __restrict__ kxT) {
    const int by = blockIdx.y;
    const bool isK = by < 16;
    const int b  = by & 15;
    const int bm = blockIdx.x * 32;
    const int lane = threadIdx.x & 63, w = threadIdx.x >> 6;
    const int wn = w * 32;
    const int r = lane & 15, ko4 = lane >> 4, ko = ko4 * 8;

    const float* X = isK ? K : Q;
    const unsigned short* WT = isK ? wkT : wqT;
    unsigned short* OUT = isK ? kxh : qxh;

    const unsigned short* Bb = WT + (size_t)(b & 7) * 131072 + (size_t)(wn + r) * 1024 + ko;
    const float* Ab = X + (size_t)b * 1048576 + (size_t)(bm + r) * 1024 + ko;
    f32x4 acc[2][2] = {};

    for (int k = 0; k < 1024; k += 32) {
        s8b a0, a1;
        float4 u0 = *(const float4*)(Ab + k);
        float4 u1 = *(const float4*)(Ab + k + 4);
        a0[0]=(short)bfr(u0.x); a0[1]=(short)bfr(u0.y);
        a0[2]=(short)bfr(u0.z); a0[3]=(short)bfr(u0.w);
        a0[4]=(short)bfr(u1.x); a0[5]=(short)bfr(u1.y);
        a0[6]=(short)bfr(u1.z); a0[7]=(short)bfr(u1.w);
        float4 v0 = *(const float4*)(Ab + (size_t)16 * 1024 + k);
        float4 v1 = *(const float4*)(Ab + (size_t)16 * 1024 + k + 4);
        a1[0]=(short)bfr(v0.x); a1[1]=(short)bfr(v0.y);
        a1[2]=(short)bfr(v0.z); a1[3]=(short)bfr(v0.w);
        a1[4]=(short)bfr(v1.x); a1[5]=(short)bfr(v1.y);
        a1[6]=(short)bfr(v1.z); a1[7]=(short)bfr(v1.w);
        s8b b0 = *(const s8b*)(Bb + k);
        s8b b1 = *(const s8b*)(Bb + (size_t)16 * 1024 + k);
        acc[0][0] = MFMA(a0, b0, acc[0][0]);
        acc[0][1] = MFMA(a0, b1, acc[0][1]);
        acc[1][0] = MFMA(a1, b0, acc[1][0]);
        acc[1][1] = MFMA(a1, b1, acc[1][1]);
    }
#pragma unroll
    for (int i = 0; i < 2; ++i)
#pragma unroll
    for (int j = 0; j < 2; ++j) {
        const int row0 = bm + i * 16 + ko4 * 4;
        const int col  = wn + j * 16 + r;
        unsigned short h0 = bfr(acc[i][j][0]);
        unsigned short h1 = bfr(acc[i][j][1]);
        unsigned short h2 = bfr(acc[i][j][2]);
        unsigned short h3 = bfr(acc[i][j][3]);
        OUT[((size_t)b * SEQ + row0 + 0) * HDIM + col] = h0;
        OUT[((size_t)b * SEQ + row0 + 1) * HDIM + col] = h1;
        OUT[((size_t)b * SEQ + row0 + 2) * HDIM + col] = h2;
        OUT[((size_t)b * SEQ + row0 + 3) * HDIM + col] = h3;
        if (isK) {   // kxT[b][col][row0..row0+3] -- contiguous 8 B
            uint2 pk;
            pk.x = (unsigned)h0 | ((unsigned)h1 << 16);
            pk.y = (unsigned)h2 | ((unsigned)h3 << 16);
            *(uint2*)(kxT + ((size_t)b * HDIM + col) * SEQ + row0) = pk;
        }
    }
}

// ---------- fused score+softmax+PV+projout+replicas(last) ----------
__global__ __launch_bounds__(256) void fused_attn(
        const unsigned short* __restrict__ qxh, const unsigned short* __restrict__ kxh,
        const unsigned short* __restrict__ kxT, const unsigned short* __restrict__ weffb,
        const float* __restrict__ proj_b, const int* __restrict__ mlen,
        float* __restrict__ attn0, float* __restrict__ out0, int wr_all,
        int skip_sweep) {
    __shared__ unsigned short Ph[16][1048];    // bf16 P   (33.5 KB)
    __shared__ unsigned short PVa[16][132];    // bf16 PV  (4.2 KB)
    __shared__ float redm[4][16];
    __shared__ float redl[4][16];

    // XCD-chunk swizzle
    const int flat = blockIdx.y * 64 + blockIdx.x;         // 0..1023
    const int work = (flat & 7) * 128 + (flat >> 3);       // bijective
    const int b  = work >> 6;
    const int q0 = (work & 63) * 16;

    const int t = threadIdx.x, w = t >> 6, lane = t & 63;
    const int r = lane & 15, ko4 = lane >> 4, ko = ko4 * 8;
    const int d = r & 3;
    const int cb = r & 12;
    const int trow = ko4 * 4 + d;
    const int ml = mlen[b];

    s8b aq[4];
#pragma unroll
    for (int ks = 0; ks < 4; ++ks)
        aq[ks] = *(const s8b*)(qxh + ((size_t)b * SEQ + q0 + r) * HDIM + ks * 32 + ko);

    // ---- phase 1: scores ----
    f32x4 sacc[16];
#pragma unroll
    for (int i = 0; i < 16; ++i) {
        const int n0 = (w + 4 * i) * 16;
        f32x4 acc = {};
#pragma unroll
        for (int ks = 0; ks < 4; ++ks) {
            s8b bk = *(const s8b*)(kxh + ((size_t)b * SEQ + n0 + r) * HDIM + ks * 32 + ko);
            acc = MFMA(aq[ks], bk, acc);
        }
        sacc[i] = acc;
    }

    // ---- softmax ----
    float pm[4] = {-3.0e38f, -3.0e38f, -3.0e38f, -3.0e38f};
#pragma unroll
    for (int i = 0; i < 16; ++i) {
        const int col = (w + 4 * i) * 16 + r;
#pragma unroll
        for (int jj = 0; jj < 4; ++jj) {
            float x = sacc[i][jj] * RSQRT_H;
            x = (col < ml) ? x : -10000.0f;
            sacc[i][jj] = x;
            pm[jj] = fmaxf(pm[jj], x);
        }
    }
#pragma unroll
    for (int dd = 1; dd < 16; dd <<= 1)
#pragma unroll
        for (int jj = 0; jj < 4; ++jj) pm[jj] = fmaxf(pm[jj], __shfl_xor(pm[jj], dd));
    if (r == 0) {
#pragma unroll
        for (int jj = 0; jj < 4; ++jj) redm[w][ko4 * 4 + jj] = pm[jj];
    }
    __syncthreads();
    float m[4];
#pragma unroll
    for (int jj = 0; jj < 4; ++jj) {
        const int row = ko4 * 4 + jj;
        m[jj] = fmaxf(fmaxf(redm[0][row], redm[1][row]),
                      fmaxf(redm[2][row], redm[3][row]));
    }
    float pl[4] = {0.f, 0.f, 0.f, 0.f};
#pragma unroll
    for (int i = 0; i < 16; ++i)
#pragma unroll
        for (int jj = 0; jj < 4; ++jj) {
            float e = __expf(sacc[i][jj] - m[jj]);
            sacc[i][jj] = e;
            pl[jj] += e;
        }
#pragma unroll
    for (int dd = 1; dd < 16; dd <<= 1)
#pragma unroll
        for (int jj = 0; jj < 4; ++jj) pl[jj] += __shfl_xor(pl[jj], dd);
    if (r == 0) {
#pragma unroll
        for (int jj = 0; jj < 4; ++jj) redl[w][ko4 * 4 + jj] = pl[jj];
    }
    __syncthreads();
    float li[4];
#pragma unroll
    for (int jj = 0; jj < 4; ++jj) {
        const int row = ko4 * 4 + jj;
        li[jj] = 1.0f / (redl[0][row] + redl[1][row] + redl[2][row] + redl[3][row]);
    }

    // ---- phase 2a: normalize + quad-transpose -> bf16 P in LDS ----
#pragma unroll
    for (int i = 0; i < 16; ++i) {
        const int n0 = (w + 4 * i) * 16;
        float y[4], z[4];
#pragma unroll
        for (int jj = 0; jj < 4; ++jj) y[jj] = sacc[i][jj] * li[jj];
        quad_transpose(d, y, z);
        uint2 pk;
        pk.x = (unsigned)bfr(z[0]) | ((unsigned)bfr(z[1]) << 16);
        pk.y = (unsigned)bfr(z[2]) | ((unsigned)bfr(z[3]) << 16);
        *(uint2*)(&Ph[trow][n0 + cb]) = pk;
    }
    __syncthreads();

    // ---- phase 3: PV = P @ kx ----
    f32x4 acc2[2] = {};
    for (int ks = 0; ks < 32; ++ks) {
        s8b pa = *(const s8b*)(&Ph[r][ks * 32 + ko]);
#pragma unroll
        for (int c = 0; c < 2; ++c) {
            const int n0 = (w * 2 + c) * 16;
            s8b bk = *(const s8b*)(kxT + ((size_t)b * HDIM + n0 + r) * SEQ + ks * 32 + ko);
            acc2[c] = MFMA(pa, bk, acc2[c]);
        }
    }
#pragma unroll
    for (int c = 0; c < 2; ++c) {
        const int n0 = (w * 2 + c) * 16;
#pragma unroll
        for (int jj = 0; jj < 4; ++jj)
            PVa[ko4 * 4 + jj][n0 + r] = bfr(acc2[c][jj]);
    }
    __syncthreads();

    // ---- phase 4: out0 = PV @ weff^T + proj_b ----
    s8b av[4];
#pragma unroll
    for (int ks = 0; ks < 4; ++ks)
        av[ks] = *(const s8b*)(&PVa[r][ks * 32 + ko]);
    float* ob = out0 + (size_t)b * SEQ * EDIM + (size_t)(q0 + trow) * EDIM;
#pragma unroll
    for (int i = 0; i < 16; ++i) {
        const int e0 = (w + 4 * i) * 16;
        f32x4 acc = {};
#pragma unroll
        for (int ks = 0; ks < 4; ++ks) {
            s8b bk = *(const s8b*)(weffb + (size_t)(e0 + r) * HDIM + ks * 32 + ko);
            acc = MFMA(av[ks], bk, acc);
        }
        float y[4] = {acc[0], acc[1], acc[2], acc[3]}, z[4];
        quad_transpose(d, y, z);
        f4v bias4 = *(const f4v*)(proj_b + e0 + cb);
        f4v o4 = {z[0] + bias4.x, z[1] + bias4.y, z[2] + bias4.z, z[3] + bias4.w};
        *(f4v*)(ob + e0 + cb) = o4;
    }

    // ---- phase 2b (LAST): contiguous replica sweep (skippable for ablation) ----
    if (!skip_sweep) {
        const size_t RB = (size_t)NBATCH * SEQ * SEQ;
        float* base0 = attn0 + (size_t)b * SEQ * SEQ + (size_t)q0 * SEQ + t * 4;
        const bool wr2 = wr_all || (b >= 5);
#pragma unroll
        for (int row = 0; row < 16; ++row) {
            ushort4 ph4 = *(const ushort4*)(&Ph[row][t * 4]);
            f4v y4 = {bf2f(ph4.x), bf2f(ph4.y), bf2f(ph4.z), bf2f(ph4.w)};
            float* p0 = base0 + (size_t)row * SEQ;
            *(f4v*)(p0)          = y4;
            *(f4v*)(p0 + RB)     = y4;
            *(f4v*)(p0 + 3 * RB) = y4;
            *(f4v*)(p0 + 4 * RB) = y4;
            *(f4v*)(p0 + 5 * RB) = y4;
            *(f4v*)(p0 + 6 * RB) = y4;
            *(f4v*)(p0 + 7 * RB) = y4;
            if (wr2) *(f4v*)(p0 + 2 * RB) = y4;
        }
    }
}

// ---------- fixup (fallback only): block0 slices 0..4 -> block2 ----------
__global__ __launch_bounds__(256) void fixup_kernel(const uint4* __restrict__ src,
                                                    uint4* __restrict__ dst) {
    size_t i = (size_t)blockIdx.x * 256 + threadIdx.x;   // 0 .. 1,310,719
    dst[i] = src[i];
}

extern "C" void kernel_launch(void* const* d_in, const int* in_sizes, int n_in,
                              void* d_out, int out_size, void* d_ws, size_t ws_size,
                              hipStream_t stream) {
    const float* k      = (const float*)d_in[0];
    const float* q      = (const float*)d_in[1];
    const float* w_kx   = (const float*)d_in[2];
    const float* w_qx   = (const float*)d_in[3];
    const float* proj_w = (const float*)d_in[4];
    const float* proj_b = (const float*)d_in[5];
    const int*   mlen   = (const int*)d_in[6];

    float* out0  = (float*)d_out;
    float* attn0 = out0 + (size_t)NBATCH * SEQ * EDIM;          // replica block 0
    const size_t BLK = (size_t)NBATCH * SEQ * SEQ;              // 16,777,216 f32

    const size_t SCRATCH_SHORTS = 1048576ull * 2 + 131072 + 2097152ull * 3; // 8,519,424
    const size_t NEED = SCRATCH_SHORTS * 2;                     // 17,038,848 B
    const int use_ws = (ws_size >= NEED) ? 1 : 0;

    unsigned short* sc16 = use_ws ? (unsigned short*)d_ws
                                  : (unsigned short*)(attn0 + 2 * BLK);
    unsigned short* wkT   = sc16;                    // 1,048,576 sh
    unsigned short* wqT   = wkT + 1048576;           // 1,048,576
    unsigned short* weffb = wqT + 1048576;           //   131,072
    unsigned short* qxh   = weffb + 131072;          // 2,097,152
    unsigned short* kxh   = qxh + 2097152;           // 2,097,152
    unsigned short* kxT   = kxh + 2097152;           // 2,097,152

    prep_kernel<<<2560, 256, 0, stream>>>(w_kx, w_qx, proj_w, wkT, wqT, weffb);

    projx_mfma<<<dim3(32, 32), 256, 0, stream>>>(k, q, wkT, wqT, kxh, qxh, kxT);

    // ABLATION launch: all compute + out0, no replica sweep (idempotent; overwritten
    // by the real launch below). dur - 281.5 isolates fused's compute+out0 time.
    fused_attn<<<dim3(64, 16), 256, 0, stream>>>(qxh, kxh, kxT, weffb, proj_b,
                                                 mlen, attn0, out0, use_ws, 1);

    // real launch
    fused_attn<<<dim3(64, 16), 256, 0, stream>>>(qxh, kxh, kxT, weffb, proj_b,
                                                 mlen, attn0, out0, use_ws, 0);

    if (!use_ws)
        fixup_kernel<<<5120, 256, 0, stream>>>((const uint4*)attn0,
                                               (uint4*)(attn0 + 2 * BLK));
}

// Round 19
// 302.824 us; speedup vs baseline: 1.2243x; 1.2243x over previous
//
#include <hip/hip_runtime.h>
#include <hip/hip_bf16.h>

#define NBATCH 16
#define SEQ    1024
#define EDIM   1024
#define HDIM   128
#define RSQRT_H 0.08838834764831845f   // 1/sqrt(128)

// d_out layout (f32): out0[16][1024][1024] | attn[128][1024][1024] (8 replica blocks of 16)
// Scratch (17.04 MB): wkT[8][128][1024]bf16 | wqT | weffb[1024][128]bf16
//                     | qxh[16][1024][128]bf16 | kxh | kxT[16][128][1024]bf16
// Primary: scratch in d_ws -> fused writes all 8 replica blocks.
// Fallback: scratch at start of attn block 2; fused skips block2 for b<5; fixup copies
//           block0 slices 0..4 -> block2 afterwards.
// Chain: prep -> projx (16-row tiles, 100% occupancy) -> fused (R14) -> [fixup]
// R19 = R14 + projx rework: measured split (R18 ablation) put prep+projx at ~125us vs
// ~30us floor -> latency-bound at 4 blocks/CU. 16-row tiles double occupancy to 32
// waves/CU and halve per-wave serial work. Fragment math unchanged (bit-identical).

typedef short s8b  __attribute__((ext_vector_type(8)));
typedef float f32x4 __attribute__((ext_vector_type(4)));
typedef float f4v  __attribute__((ext_vector_type(4)));

__device__ __forceinline__ unsigned short bfr(float f) {   // f32 -> bf16 bits, RNE
    unsigned u = __float_as_uint(f);
    u += 0x7fffu + ((u >> 16) & 1u);
    return (unsigned short)(u >> 16);
}

__device__ __forceinline__ float bf2f(unsigned short h) {  // bf16 bits -> f32
    return __uint_as_float((unsigned)h << 16);
}

__device__ __forceinline__ f32x4 MFMA(s8b a, s8b b, f32x4 c) {
    return __builtin_amdgcn_mfma_f32_16x16x32_bf16(a, b, c, 0, 0, 0);
}

// 4x4 transpose within a quad
__device__ __forceinline__ void quad_transpose(int d, const float y[4], float z[4]) {
    float s0 = (d & 1) ? y[0] : y[1];
    float g0 = __shfl_xor(s0, 1);
    float s1 = (d & 1) ? y[2] : y[3];
    float g1 = __shfl_xor(s1, 1);
    float B0 = (d & 1) ? g0 : y[0];
    float B1 = (d & 1) ? y[1] : g0;
    float B2 = (d & 1) ? g1 : y[2];
    float B3 = (d & 1) ? y[3] : g1;
    float s2 = (d & 2) ? B0 : B2;
    float h0 = __shfl_xor(s2, 2);
    float s3 = (d & 2) ? B1 : B3;
    float h1 = __shfl_xor(s3, 2);
    z[0] = (d & 2) ? h0 : B0;
    z[1] = (d & 2) ? h1 : B1;
    z[2] = (d & 2) ? B2 : h0;
    z[3] = (d & 2) ? B3 : h1;
}

// ---------- prep: weff fold + w_kx/w_qx transposes, one dispatch ----------
__global__ __launch_bounds__(256) void prep_kernel(const float* __restrict__ w_kx,
                                                   const float* __restrict__ w_qx,
                                                   const float* __restrict__ proj_w,
                                                   unsigned short* __restrict__ wkT,
                                                   unsigned short* __restrict__ wqT,
                                                   unsigned short* __restrict__ weffb) {
    __shared__ unsigned short tile[32][40];
    const int blk = blockIdx.x;
    const int t = threadIdx.x;
    if (blk < 2048) {
        const int idx = blk & 1023;
        const float* src = (blk < 1024) ? w_kx : w_qx;
        unsigned short* dst = (blk < 1024) ? wkT : wqT;
        const int e0 = (idx & 31) * 32, h0 = ((idx >> 5) & 3) * 32, hd = idx >> 7;
        const int r = t >> 3, c = (t & 7) * 4;
        float4 v = *(const float4*)(src + ((size_t)hd * 1024 + e0 + r) * 128 + h0 + c);
        tile[r][c]     = bfr(v.x);
        tile[r][c + 1] = bfr(v.y);
        tile[r][c + 2] = bfr(v.z);
        tile[r][c + 3] = bfr(v.w);
        __syncthreads();
        ushort4 o;
        o.x = tile[c][r]; o.y = tile[c + 1][r]; o.z = tile[c + 2][r]; o.w = tile[c + 3][r];
        *(ushort4*)(dst + ((size_t)hd * 128 + h0 + r) * 1024 + e0 + c) = o;
    } else {
        int i = (blk - 2048) * 256 + t;          // 0..131071
        int e = i >> 7, h = i & 127;
        const float* p = proj_w + (size_t)e * (8 * HDIM) + h;
        float s = 0.f;
#pragma unroll
        for (int j = 0; j < 8; ++j) s += p[j * HDIM];
        weffb[i] = bfr(s);
    }
}

// ---------- projx: 16-row tiles, 2048 blocks, XCD-chunked ----------
// work = batch*64 + mtile; grid (64, 32): by<16 -> k, else q
__global__ __launch_bounds__(256) void projx_mfma(const float* __restrict__ K,
                                                  const float* __restrict__ Q,
                                                  const unsigned short* __restrict__ wkT,
                                                  const unsigned short* __restrict__ wqT,
                                                  unsigned short* __restrict__ kxh,
                                                  unsigned short* __restrict__ qxh,
                                                  unsigned short* __restrict__ kxT) {
    // XCD-chunk swizzle over 2048 blocks (8 x 256)
    const int flat = blockIdx.y * 64 + blockIdx.x;         // 0..2047
    const int work = (flat & 7) * 256 + (flat >> 3);       // bijective
    const int by = work >> 6;                              // 0..31
    const bool isK = by < 16;
    const int b  = by & 15;
    const int bm = (work & 63) * 16;

    const int lane = threadIdx.x & 63, w = threadIdx.x >> 6;
    const int wn = w * 32;
    const int r = lane & 15, ko4 = lane >> 4, ko = ko4 * 8;

    const float* X = isK ? K : Q;
    const unsigned short* WT = isK ? wkT : wqT;
    unsigned short* OUT = isK ? kxh : qxh;

    const unsigned short* Bb = WT + (size_t)(b & 7) * 131072 + (size_t)(wn + r) * 1024 + ko;
    const float* Ab = X + (size_t)b * 1048576 + (size_t)(bm + r) * 1024 + ko;
    f32x4 acc[2] = {};

    for (int k = 0; k < 1024; k += 32) {
        s8b a0;
        float4 u0 = *(const float4*)(Ab + k);
        float4 u1 = *(const float4*)(Ab + k + 4);
        a0[0]=(short)bfr(u0.x); a0[1]=(short)bfr(u0.y);
        a0[2]=(short)bfr(u0.z); a0[3]=(short)bfr(u0.w);
        a0[4]=(short)bfr(u1.x); a0[5]=(short)bfr(u1.y);
        a0[6]=(short)bfr(u1.z); a0[7]=(short)bfr(u1.w);
        s8b b0 = *(const s8b*)(Bb + k);
        s8b b1 = *(const s8b*)(Bb + (size_t)16 * 1024 + k);
        acc[0] = MFMA(a0, b0, acc[0]);
        acc[1] = MFMA(a0, b1, acc[1]);
    }
#pragma unroll
    for (int j = 0; j < 2; ++j) {
        const int row0 = bm + ko4 * 4;
        const int col  = wn + j * 16 + r;
        unsigned short h0 = bfr(acc[j][0]);
        unsigned short h1 = bfr(acc[j][1]);
        unsigned short h2 = bfr(acc[j][2]);
        unsigned short h3 = bfr(acc[j][3]);
        OUT[((size_t)b * SEQ + row0 + 0) * HDIM + col] = h0;
        OUT[((size_t)b * SEQ + row0 + 1) * HDIM + col] = h1;
        OUT[((size_t)b * SEQ + row0 + 2) * HDIM + col] = h2;
        OUT[((size_t)b * SEQ + row0 + 3) * HDIM + col] = h3;
        if (isK) {   // kxT[b][col][row0..row0+3] -- contiguous 8 B
            uint2 pk;
            pk.x = (unsigned)h0 | ((unsigned)h1 << 16);
            pk.y = (unsigned)h2 | ((unsigned)h3 << 16);
            *(uint2*)(kxT + ((size_t)b * HDIM + col) * SEQ + row0) = pk;
        }
    }
}

// ---------- fused score+softmax+PV+projout+replicas(last) -- R14 exact ----------
__global__ __launch_bounds__(256) void fused_attn(
        const unsigned short* __restrict__ qxh, const unsigned short* __restrict__ kxh,
        const unsigned short* __restrict__ kxT, const unsigned short* __restrict__ weffb,
        const float* __restrict__ proj_b, const int* __restrict__ mlen,
        float* __restrict__ attn0, float* __restrict__ out0, int wr_all) {
    __shared__ unsigned short Ph[16][1048];    // bf16 P   (33.5 KB)
    __shared__ unsigned short PVa[16][132];    // bf16 PV  (4.2 KB)
    __shared__ float redm[4][16];
    __shared__ float redl[4][16];

    // XCD-chunk swizzle
    const int flat = blockIdx.y * 64 + blockIdx.x;         // 0..1023
    const int work = (flat & 7) * 128 + (flat >> 3);       // bijective
    const int b  = work >> 6;
    const int q0 = (work & 63) * 16;

    const int t = threadIdx.x, w = t >> 6, lane = t & 63;
    const int r = lane & 15, ko4 = lane >> 4, ko = ko4 * 8;
    const int d = r & 3;
    const int cb = r & 12;
    const int trow = ko4 * 4 + d;
    const int ml = mlen[b];

    s8b aq[4];
#pragma unroll
    for (int ks = 0; ks < 4; ++ks)
        aq[ks] = *(const s8b*)(qxh + ((size_t)b * SEQ + q0 + r) * HDIM + ks * 32 + ko);

    // ---- phase 1: scores ----
    f32x4 sacc[16];
#pragma unroll
    for (int i = 0; i < 16; ++i) {
        const int n0 = (w + 4 * i) * 16;
        f32x4 acc = {};
#pragma unroll
        for (int ks = 0; ks < 4; ++ks) {
            s8b bk = *(const s8b*)(kxh + ((size_t)b * SEQ + n0 + r) * HDIM + ks * 32 + ko);
            acc = MFMA(aq[ks], bk, acc);
        }
        sacc[i] = acc;
    }

    // ---- softmax ----
    float pm[4] = {-3.0e38f, -3.0e38f, -3.0e38f, -3.0e38f};
#pragma unroll
    for (int i = 0; i < 16; ++i) {
        const int col = (w + 4 * i) * 16 + r;
#pragma unroll
        for (int jj = 0; jj < 4; ++jj) {
            float x = sacc[i][jj] * RSQRT_H;
            x = (col < ml) ? x : -10000.0f;
            sacc[i][jj] = x;
            pm[jj] = fmaxf(pm[jj], x);
        }
    }
#pragma unroll
    for (int dd = 1; dd < 16; dd <<= 1)
#pragma unroll
        for (int jj = 0; jj < 4; ++jj) pm[jj] = fmaxf(pm[jj], __shfl_xor(pm[jj], dd));
    if (r == 0) {
#pragma unroll
        for (int jj = 0; jj < 4; ++jj) redm[w][ko4 * 4 + jj] = pm[jj];
    }
    __syncthreads();
    float m[4];
#pragma unroll
    for (int jj = 0; jj < 4; ++jj) {
        const int row = ko4 * 4 + jj;
        m[jj] = fmaxf(fmaxf(redm[0][row], redm[1][row]),
                      fmaxf(redm[2][row], redm[3][row]));
    }
    float pl[4] = {0.f, 0.f, 0.f, 0.f};
#pragma unroll
    for (int i = 0; i < 16; ++i)
#pragma unroll
        for (int jj = 0; jj < 4; ++jj) {
            float e = __expf(sacc[i][jj] - m[jj]);
            sacc[i][jj] = e;
            pl[jj] += e;
        }
#pragma unroll
    for (int dd = 1; dd < 16; dd <<= 1)
#pragma unroll
        for (int jj = 0; jj < 4; ++jj) pl[jj] += __shfl_xor(pl[jj], dd);
    if (r == 0) {
#pragma unroll
        for (int jj = 0; jj < 4; ++jj) redl[w][ko4 * 4 + jj] = pl[jj];
    }
    __syncthreads();
    float li[4];
#pragma unroll
    for (int jj = 0; jj < 4; ++jj) {
        const int row = ko4 * 4 + jj;
        li[jj] = 1.0f / (redl[0][row] + redl[1][row] + redl[2][row] + redl[3][row]);
    }

    // ---- phase 2a: normalize + quad-transpose -> bf16 P in LDS ----
#pragma unroll
    for (int i = 0; i < 16; ++i) {
        const int n0 = (w + 4 * i) * 16;
        float y[4], z[4];
#pragma unroll
        for (int jj = 0; jj < 4; ++jj) y[jj] = sacc[i][jj] * li[jj];
        quad_transpose(d, y, z);
        uint2 pk;
        pk.x = (unsigned)bfr(z[0]) | ((unsigned)bfr(z[1]) << 16);
        pk.y = (unsigned)bfr(z[2]) | ((unsigned)bfr(z[3]) << 16);
        *(uint2*)(&Ph[trow][n0 + cb]) = pk;
    }
    __syncthreads();

    // ---- phase 3: PV = P @ kx ----
    f32x4 acc2[2] = {};
    for (int ks = 0; ks < 32; ++ks) {
        s8b pa = *(const s8b*)(&Ph[r][ks * 32 + ko]);
#pragma unroll
        for (int c = 0; c < 2; ++c) {
            const int n0 = (w * 2 + c) * 16;
            s8b bk = *(const s8b*)(kxT + ((size_t)b * HDIM + n0 + r) * SEQ + ks * 32 + ko);
            acc2[c] = MFMA(pa, bk, acc2[c]);
        }
    }
#pragma unroll
    for (int c = 0; c < 2; ++c) {
        const int n0 = (w * 2 + c) * 16;
#pragma unroll
        for (int jj = 0; jj < 4; ++jj)
            PVa[ko4 * 4 + jj][n0 + r] = bfr(acc2[c][jj]);
    }
    __syncthreads();

    // ---- phase 4: out0 = PV @ weff^T + proj_b ----
    s8b av[4];
#pragma unroll
    for (int ks = 0; ks < 4; ++ks)
        av[ks] = *(const s8b*)(&PVa[r][ks * 32 + ko]);
    float* ob = out0 + (size_t)b * SEQ * EDIM + (size_t)(q0 + trow) * EDIM;
#pragma unroll
    for (int i = 0; i < 16; ++i) {
        const int e0 = (w + 4 * i) * 16;
        f32x4 acc = {};
#pragma unroll
        for (int ks = 0; ks < 4; ++ks) {
            s8b bk = *(const s8b*)(weffb + (size_t)(e0 + r) * HDIM + ks * 32 + ko);
            acc = MFMA(av[ks], bk, acc);
        }
        float y[4] = {acc[0], acc[1], acc[2], acc[3]}, z[4];
        quad_transpose(d, y, z);
        f4v bias4 = *(const f4v*)(proj_b + e0 + cb);
        f4v o4 = {z[0] + bias4.x, z[1] + bias4.y, z[2] + bias4.z, z[3] + bias4.w};
        *(f4v*)(ob + e0 + cb) = o4;
    }

    // ---- phase 2b (LAST): contiguous replica sweep ----
    {
        const size_t RB = (size_t)NBATCH * SEQ * SEQ;
        float* base0 = attn0 + (size_t)b * SEQ * SEQ + (size_t)q0 * SEQ + t * 4;
        const bool wr2 = wr_all || (b >= 5);
#pragma unroll
        for (int row = 0; row < 16; ++row) {
            ushort4 ph4 = *(const ushort4*)(&Ph[row][t * 4]);
            f4v y4 = {bf2f(ph4.x), bf2f(ph4.y), bf2f(ph4.z), bf2f(ph4.w)};
            float* p0 = base0 + (size_t)row * SEQ;
            *(f4v*)(p0)          = y4;
            *(f4v*)(p0 + RB)     = y4;
            *(f4v*)(p0 + 3 * RB) = y4;
            *(f4v*)(p0 + 4 * RB) = y4;
            *(f4v*)(p0 + 5 * RB) = y4;
            *(f4v*)(p0 + 6 * RB) = y4;
            *(f4v*)(p0 + 7 * RB) = y4;
            if (wr2) *(f4v*)(p0 + 2 * RB) = y4;
        }
    }
}

// ---------- fixup (fallback only): block0 slices 0..4 -> block2 ----------
__global__ __launch_bounds__(256) void fixup_kernel(const uint4* __restrict__ src,
                                                    uint4* __restrict__ dst) {
    size_t i = (size_t)blockIdx.x * 256 + threadIdx.x;   // 0 .. 1,310,719
    dst[i] = src[i];
}

extern "C" void kernel_launch(void* const* d_in, const int* in_sizes, int n_in,
                              void* d_out, int out_size, void* d_ws, size_t ws_size,
                              hipStream_t stream) {
    const float* k      = (const float*)d_in[0];
    const float* q      = (const float*)d_in[1];
    const float* w_kx   = (const float*)d_in[2];
    const float* w_qx   = (const float*)d_in[3];
    const float* proj_w = (const float*)d_in[4];
    const float* proj_b = (const float*)d_in[5];
    const int*   mlen   = (const int*)d_in[6];

    float* out0  = (float*)d_out;
    float* attn0 = out0 + (size_t)NBATCH * SEQ * EDIM;          // replica block 0
    const size_t BLK = (size_t)NBATCH * SEQ * SEQ;              // 16,777,216 f32

    const size_t SCRATCH_SHORTS = 1048576ull * 2 + 131072 + 2097152ull * 3; // 8,519,424
    const size_t NEED = SCRATCH_SHORTS * 2;                     // 17,038,848 B
    const int use_ws = (ws_size >= NEED) ? 1 : 0;

    unsigned short* sc16 = use_ws ? (unsigned short*)d_ws
                                  : (unsigned short*)(attn0 + 2 * BLK);
    unsigned short* wkT   = sc16;                    // 1,048,576 sh
    unsigned short* wqT   = wkT + 1048576;           // 1,048,576
    unsigned short* weffb = wqT + 1048576;           //   131,072
    unsigned short* qxh   = weffb + 131072;          // 2,097,152
    unsigned short* kxh   = qxh + 2097152;           // 2,097,152
    unsigned short* kxT   = kxh + 2097152;           // 2,097,152

    prep_kernel<<<2560, 256, 0, stream>>>(w_kx, w_qx, proj_w, wkT, wqT, weffb);

    projx_mfma<<<dim3(64, 32), 256, 0, stream>>>(k, q, wkT, wqT, kxh, qxh, kxT);

    fused_attn<<<dim3(64, 16), 256, 0, stream>>>(qxh, kxh, kxT, weffb, proj_b,
                                                 mlen, attn0, out0, use_ws);

    if (!use_ws)
        fixup_kernel<<<5120, 256, 0, stream>>>((const uint4*)attn0,
                                               (uint4*)(attn0 + 2 * BLK));
}

// Round 20
// 276.453 us; speedup vs baseline: 1.3411x; 1.0954x over previous
//
#include <hip/hip_runtime.h>
#include <hip/hip_bf16.h>

#define NBATCH 16
#define SEQ    1024
#define EDIM   1024
#define HDIM   128
#define RSQRT_H 0.08838834764831845f   // 1/sqrt(128)

// d_out layout (f32): out0[16][1024][1024] | attn[128][1024][1024] (8 replica blocks of 16)
// Scratch (17.04 MB): wkT[8][128][1024]bf16 | wqT | weffb[1024][128]bf16
//                     | qxh[16][1024][128]bf16 | kxh | kxT[16][128][1024]bf16
// Primary: scratch in d_ws -> fused writes all 8 replica blocks.
// Fallback: scratch at start of attn block 2; fused skips block2 for b<5; fixup copies
//           block0 slices 0..4 -> block2 afterwards.
// Chain: prep -> projx -> fused -> [fixup]
// R20 = R14 exact + projx k-loop 1-deep register prefetch (loads for iter k+32 issued
// before compute of iter k -> breaks the per-iteration waitcnt-at-first-use serial
// drain hipcc otherwise emits). Outputs bit-identical to R14.

typedef short s8b  __attribute__((ext_vector_type(8)));
typedef float f32x4 __attribute__((ext_vector_type(4)));
typedef float f4v  __attribute__((ext_vector_type(4)));

__device__ __forceinline__ unsigned short bfr(float f) {   // f32 -> bf16 bits, RNE
    unsigned u = __float_as_uint(f);
    u += 0x7fffu + ((u >> 16) & 1u);
    return (unsigned short)(u >> 16);
}

__device__ __forceinline__ float bf2f(unsigned short h) {  // bf16 bits -> f32
    return __uint_as_float((unsigned)h << 16);
}

__device__ __forceinline__ f32x4 MFMA(s8b a, s8b b, f32x4 c) {
    return __builtin_amdgcn_mfma_f32_16x16x32_bf16(a, b, c, 0, 0, 0);
}

// 4x4 transpose within a quad
__device__ __forceinline__ void quad_transpose(int d, const float y[4], float z[4]) {
    float s0 = (d & 1) ? y[0] : y[1];
    float g0 = __shfl_xor(s0, 1);
    float s1 = (d & 1) ? y[2] : y[3];
    float g1 = __shfl_xor(s1, 1);
    float B0 = (d & 1) ? g0 : y[0];
    float B1 = (d & 1) ? y[1] : g0;
    float B2 = (d & 1) ? g1 : y[2];
    float B3 = (d & 1) ? y[3] : g1;
    float s2 = (d & 2) ? B0 : B2;
    float h0 = __shfl_xor(s2, 2);
    float s3 = (d & 2) ? B1 : B3;
    float h1 = __shfl_xor(s3, 2);
    z[0] = (d & 2) ? h0 : B0;
    z[1] = (d & 2) ? h1 : B1;
    z[2] = (d & 2) ? B2 : h0;
    z[3] = (d & 2) ? B3 : h1;
}

__device__ __forceinline__ void pack8(const float4& a, const float4& b, s8b& o) {
    o[0]=(short)bfr(a.x); o[1]=(short)bfr(a.y); o[2]=(short)bfr(a.z); o[3]=(short)bfr(a.w);
    o[4]=(short)bfr(b.x); o[5]=(short)bfr(b.y); o[6]=(short)bfr(b.z); o[7]=(short)bfr(b.w);
}

// ---------- prep: weff fold + w_kx/w_qx transposes, one dispatch ----------
__global__ __launch_bounds__(256) void prep_kernel(const float* __restrict__ w_kx,
                                                   const float* __restrict__ w_qx,
                                                   const float* __restrict__ proj_w,
                                                   unsigned short* __restrict__ wkT,
                                                   unsigned short* __restrict__ wqT,
                                                   unsigned short* __restrict__ weffb) {
    __shared__ unsigned short tile[32][40];
    const int blk = blockIdx.x;
    const int t = threadIdx.x;
    if (blk < 2048) {
        const int idx = blk & 1023;
        const float* src = (blk < 1024) ? w_kx : w_qx;
        unsigned short* dst = (blk < 1024) ? wkT : wqT;
        const int e0 = (idx & 31) * 32, h0 = ((idx >> 5) & 3) * 32, hd = idx >> 7;
        const int r = t >> 3, c = (t & 7) * 4;
        float4 v = *(const float4*)(src + ((size_t)hd * 1024 + e0 + r) * 128 + h0 + c);
        tile[r][c]     = bfr(v.x);
        tile[r][c + 1] = bfr(v.y);
        tile[r][c + 2] = bfr(v.z);
        tile[r][c + 3] = bfr(v.w);
        __syncthreads();
        ushort4 o;
        o.x = tile[c][r]; o.y = tile[c + 1][r]; o.z = tile[c + 2][r]; o.w = tile[c + 3][r];
        *(ushort4*)(dst + ((size_t)hd * 128 + h0 + r) * 1024 + e0 + c) = o;
    } else {
        int i = (blk - 2048) * 256 + t;          // 0..131071
        int e = i >> 7, h = i & 127;
        const float* p = proj_w + (size_t)e * (8 * HDIM) + h;
        float s = 0.f;
#pragma unroll
        for (int j = 0; j < 8; ++j) s += p[j * HDIM];
        weffb[i] = bfr(s);
    }
}

// ---------- projx: R14 geometry (32-row tiles), 1-deep software pipeline ----------
__global__ __launch_bounds__(256) void projx_mfma(const float* __restrict__ K,
                                                  const float* __restrict__ Q,
                                                  const unsigned short* __restrict__ wkT,
                                                  const unsigned short* __restrict__ wqT,
                                                  unsigned short* __restrict__ kxh,
                                                  unsigned short* __restrict__ qxh,
                                                  unsigned short* __restrict__ kxT) {
    const int by = blockIdx.y;
    const bool isK = by < 16;
    const int b  = by & 15;
    const int bm = blockIdx.x * 32;
    const int lane = threadIdx.x & 63, w = threadIdx.x >> 6;
    const int wn = w * 32;
    const int r = lane & 15, ko4 = lane >> 4, ko = ko4 * 8;

    const float* X = isK ? K : Q;
    const unsigned short* WT = isK ? wkT : wqT;
    unsigned short* OUT = isK ? kxh : qxh;

    const unsigned short* Bb = WT + (size_t)(b & 7) * 131072 + (size_t)(wn + r) * 1024 + ko;
    const float* Ab = X + (size_t)b * 1048576 + (size_t)(bm + r) * 1024 + ko;
    f32x4 acc[2][2] = {};

    // preload k=0
    float4 cu0 = *(const float4*)(Ab);
    float4 cu1 = *(const float4*)(Ab + 4);
    float4 cv0 = *(const float4*)(Ab + 16384);
    float4 cv1 = *(const float4*)(Ab + 16384 + 4);
    s8b cb0 = *(const s8b*)(Bb);
    s8b cb1 = *(const s8b*)(Bb + 16384);

    for (int k = 0; k < 992; k += 32) {
        // issue next iteration's loads FIRST (1-deep prefetch)
        float4 nu0 = *(const float4*)(Ab + k + 32);
        float4 nu1 = *(const float4*)(Ab + k + 36);
        float4 nv0 = *(const float4*)(Ab + 16384 + k + 32);
        float4 nv1 = *(const float4*)(Ab + 16384 + k + 36);
        s8b nb0 = *(const s8b*)(Bb + k + 32);
        s8b nb1 = *(const s8b*)(Bb + 16384 + k + 32);
        // compute with current (loaded one iteration ago)
        s8b a0, a1;
        pack8(cu0, cu1, a0);
        pack8(cv0, cv1, a1);
        acc[0][0] = MFMA(a0, cb0, acc[0][0]);
        acc[0][1] = MFMA(a0, cb1, acc[0][1]);
        acc[1][0] = MFMA(a1, cb0, acc[1][0]);
        acc[1][1] = MFMA(a1, cb1, acc[1][1]);
        cu0 = nu0; cu1 = nu1; cv0 = nv0; cv1 = nv1; cb0 = nb0; cb1 = nb1;
    }
    {   // epilogue: last iteration
        s8b a0, a1;
        pack8(cu0, cu1, a0);
        pack8(cv0, cv1, a1);
        acc[0][0] = MFMA(a0, cb0, acc[0][0]);
        acc[0][1] = MFMA(a0, cb1, acc[0][1]);
        acc[1][0] = MFMA(a1, cb0, acc[1][0]);
        acc[1][1] = MFMA(a1, cb1, acc[1][1]);
    }

#pragma unroll
    for (int i = 0; i < 2; ++i)
#pragma unroll
    for (int j = 0; j < 2; ++j) {
        const int row0 = bm + i * 16 + ko4 * 4;
        const int col  = wn + j * 16 + r;
        unsigned short h0 = bfr(acc[i][j][0]);
        unsigned short h1 = bfr(acc[i][j][1]);
        unsigned short h2 = bfr(acc[i][j][2]);
        unsigned short h3 = bfr(acc[i][j][3]);
        OUT[((size_t)b * SEQ + row0 + 0) * HDIM + col] = h0;
        OUT[((size_t)b * SEQ + row0 + 1) * HDIM + col] = h1;
        OUT[((size_t)b * SEQ + row0 + 2) * HDIM + col] = h2;
        OUT[((size_t)b * SEQ + row0 + 3) * HDIM + col] = h3;
        if (isK) {   // kxT[b][col][row0..row0+3] -- contiguous 8 B
            uint2 pk;
            pk.x = (unsigned)h0 | ((unsigned)h1 << 16);
            pk.y = (unsigned)h2 | ((unsigned)h3 << 16);
            *(uint2*)(kxT + ((size_t)b * HDIM + col) * SEQ + row0) = pk;
        }
    }
}

// ---------- fused score+softmax+PV+projout+replicas(last) -- R14 exact ----------
__global__ __launch_bounds__(256) void fused_attn(
        const unsigned short* __restrict__ qxh, const unsigned short* __restrict__ kxh,
        const unsigned short* __restrict__ kxT, const unsigned short* __restrict__ weffb,
        const float* __restrict__ proj_b, const int* __restrict__ mlen,
        float* __restrict__ attn0, float* __restrict__ out0, int wr_all) {
    __shared__ unsigned short Ph[16][1048];    // bf16 P   (33.5 KB)
    __shared__ unsigned short PVa[16][132];    // bf16 PV  (4.2 KB)
    __shared__ float redm[4][16];
    __shared__ float redl[4][16];

    // XCD-chunk swizzle
    const int flat = blockIdx.y * 64 + blockIdx.x;         // 0..1023
    const int work = (flat & 7) * 128 + (flat >> 3);       // bijective
    const int b  = work >> 6;
    const int q0 = (work & 63) * 16;

    const int t = threadIdx.x, w = t >> 6, lane = t & 63;
    const int r = lane & 15, ko4 = lane >> 4, ko = ko4 * 8;
    const int d = r & 3;
    const int cb = r & 12;
    const int trow = ko4 * 4 + d;
    const int ml = mlen[b];

    s8b aq[4];
#pragma unroll
    for (int ks = 0; ks < 4; ++ks)
        aq[ks] = *(const s8b*)(qxh + ((size_t)b * SEQ + q0 + r) * HDIM + ks * 32 + ko);

    // ---- phase 1: scores ----
    f32x4 sacc[16];
#pragma unroll
    for (int i = 0; i < 16; ++i) {
        const int n0 = (w + 4 * i) * 16;
        f32x4 acc = {};
#pragma unroll
        for (int ks = 0; ks < 4; ++ks) {
            s8b bk = *(const s8b*)(kxh + ((size_t)b * SEQ + n0 + r) * HDIM + ks * 32 + ko);
            acc = MFMA(aq[ks], bk, acc);
        }
        sacc[i] = acc;
    }

    // ---- softmax ----
    float pm[4] = {-3.0e38f, -3.0e38f, -3.0e38f, -3.0e38f};
#pragma unroll
    for (int i = 0; i < 16; ++i) {
        const int col = (w + 4 * i) * 16 + r;
#pragma unroll
        for (int jj = 0; jj < 4; ++jj) {
            float x = sacc[i][jj] * RSQRT_H;
            x = (col < ml) ? x : -10000.0f;
            sacc[i][jj] = x;
            pm[jj] = fmaxf(pm[jj], x);
        }
    }
#pragma unroll
    for (int dd = 1; dd < 16; dd <<= 1)
#pragma unroll
        for (int jj = 0; jj < 4; ++jj) pm[jj] = fmaxf(pm[jj], __shfl_xor(pm[jj], dd));
    if (r == 0) {
#pragma unroll
        for (int jj = 0; jj < 4; ++jj) redm[w][ko4 * 4 + jj] = pm[jj];
    }
    __syncthreads();
    float m[4];
#pragma unroll
    for (int jj = 0; jj < 4; ++jj) {
        const int row = ko4 * 4 + jj;
        m[jj] = fmaxf(fmaxf(redm[0][row], redm[1][row]),
                      fmaxf(redm[2][row], redm[3][row]));
    }
    float pl[4] = {0.f, 0.f, 0.f, 0.f};
#pragma unroll
    for (int i = 0; i < 16; ++i)
#pragma unroll
        for (int jj = 0; jj < 4; ++jj) {
            float e = __expf(sacc[i][jj] - m[jj]);
            sacc[i][jj] = e;
            pl[jj] += e;
        }
#pragma unroll
    for (int dd = 1; dd < 16; dd <<= 1)
#pragma unroll
        for (int jj = 0; jj < 4; ++jj) pl[jj] += __shfl_xor(pl[jj], dd);
    if (r == 0) {
#pragma unroll
        for (int jj = 0; jj < 4; ++jj) redl[w][ko4 * 4 + jj] = pl[jj];
    }
    __syncthreads();
    float li[4];
#pragma unroll
    for (int jj = 0; jj < 4; ++jj) {
        const int row = ko4 * 4 + jj;
        li[jj] = 1.0f / (redl[0][row] + redl[1][row] + redl[2][row] + redl[3][row]);
    }

    // ---- phase 2a: normalize + quad-transpose -> bf16 P in LDS ----
#pragma unroll
    for (int i = 0; i < 16; ++i) {
        const int n0 = (w + 4 * i) * 16;
        float y[4], z[4];
#pragma unroll
        for (int jj = 0; jj < 4; ++jj) y[jj] = sacc[i][jj] * li[jj];
        quad_transpose(d, y, z);
        uint2 pk;
        pk.x = (unsigned)bfr(z[0]) | ((unsigned)bfr(z[1]) << 16);
        pk.y = (unsigned)bfr(z[2]) | ((unsigned)bfr(z[3]) << 16);
        *(uint2*)(&Ph[trow][n0 + cb]) = pk;
    }
    __syncthreads();

    // ---- phase 3: PV = P @ kx ----
    f32x4 acc2[2] = {};
    for (int ks = 0; ks < 32; ++ks) {
        s8b pa = *(const s8b*)(&Ph[r][ks * 32 + ko]);
#pragma unroll
        for (int c = 0; c < 2; ++c) {
            const int n0 = (w * 2 + c) * 16;
            s8b bk = *(const s8b*)(kxT + ((size_t)b * HDIM + n0 + r) * SEQ + ks * 32 + ko);
            acc2[c] = MFMA(pa, bk, acc2[c]);
        }
    }
#pragma unroll
    for (int c = 0; c < 2; ++c) {
        const int n0 = (w * 2 + c) * 16;
#pragma unroll
        for (int jj = 0; jj < 4; ++jj)
            PVa[ko4 * 4 + jj][n0 + r] = bfr(acc2[c][jj]);
    }
    __syncthreads();

    // ---- phase 4: out0 = PV @ weff^T + proj_b ----
    s8b av[4];
#pragma unroll
    for (int ks = 0; ks < 4; ++ks)
        av[ks] = *(const s8b*)(&PVa[r][ks * 32 + ko]);
    float* ob = out0 + (size_t)b * SEQ * EDIM + (size_t)(q0 + trow) * EDIM;
#pragma unroll
    for (int i = 0; i < 16; ++i) {
        const int e0 = (w + 4 * i) * 16;
        f32x4 acc = {};
#pragma unroll
        for (int ks = 0; ks < 4; ++ks) {
            s8b bk = *(const s8b*)(weffb + (size_t)(e0 + r) * HDIM + ks * 32 + ko);
            acc = MFMA(av[ks], bk, acc);
        }
        float y[4] = {acc[0], acc[1], acc[2], acc[3]}, z[4];
        quad_transpose(d, y, z);
        f4v bias4 = *(const f4v*)(proj_b + e0 + cb);
        f4v o4 = {z[0] + bias4.x, z[1] + bias4.y, z[2] + bias4.z, z[3] + bias4.w};
        *(f4v*)(ob + e0 + cb) = o4;
    }

    // ---- phase 2b (LAST): contiguous replica sweep ----
    {
        const size_t RB = (size_t)NBATCH * SEQ * SEQ;
        float* base0 = attn0 + (size_t)b * SEQ * SEQ + (size_t)q0 * SEQ + t * 4;
        const bool wr2 = wr_all || (b >= 5);
#pragma unroll
        for (int row = 0; row < 16; ++row) {
            ushort4 ph4 = *(const ushort4*)(&Ph[row][t * 4]);
            f4v y4 = {bf2f(ph4.x), bf2f(ph4.y), bf2f(ph4.z), bf2f(ph4.w)};
            float* p0 = base0 + (size_t)row * SEQ;
            *(f4v*)(p0)          = y4;
            *(f4v*)(p0 + RB)     = y4;
            *(f4v*)(p0 + 3 * RB) = y4;
            *(f4v*)(p0 + 4 * RB) = y4;
            *(f4v*)(p0 + 5 * RB) = y4;
            *(f4v*)(p0 + 6 * RB) = y4;
            *(f4v*)(p0 + 7 * RB) = y4;
            if (wr2) *(f4v*)(p0 + 2 * RB) = y4;
        }
    }
}

// ---------- fixup (fallback only): block0 slices 0..4 -> block2 ----------
__global__ __launch_bounds__(256) void fixup_kernel(const uint4* __restrict__ src,
                                                    uint4* __restrict__ dst) {
    size_t i = (size_t)blockIdx.x * 256 + threadIdx.x;   // 0 .. 1,310,719
    dst[i] = src[i];
}

extern "C" void kernel_launch(void* const* d_in, const int* in_sizes, int n_in,
                              void* d_out, int out_size, void* d_ws, size_t ws_size,
                              hipStream_t stream) {
    const float* k      = (const float*)d_in[0];
    const float* q      = (const float*)d_in[1];
    const float* w_kx   = (const float*)d_in[2];
    const float* w_qx   = (const float*)d_in[3];
    const float* proj_w = (const float*)d_in[4];
    const float* proj_b = (const float*)d_in[5];
    const int*   mlen   = (const int*)d_in[6];

    float* out0  = (float*)d_out;
    float* attn0 = out0 + (size_t)NBATCH * SEQ * EDIM;          // replica block 0
    const size_t BLK = (size_t)NBATCH * SEQ * SEQ;              // 16,777,216 f32

    const size_t SCRATCH_SHORTS = 1048576ull * 2 + 131072 + 2097152ull * 3; // 8,519,424
    const size_t NEED = SCRATCH_SHORTS * 2;                     // 17,038,848 B
    const int use_ws = (ws_size >= NEED) ? 1 : 0;

    unsigned short* sc16 = use_ws ? (unsigned short*)d_ws
                                  : (unsigned short*)(attn0 + 2 * BLK);
    unsigned short* wkT   = sc16;                    // 1,048,576 sh
    unsigned short* wqT   = wkT + 1048576;           // 1,048,576
    unsigned short* weffb = wqT + 1048576;           //   131,072
    unsigned short* qxh   = weffb + 131072;          // 2,097,152
    unsigned short* kxh   = qxh + 2097152;           // 2,097,152
    unsigned short* kxT   = kxh + 2097152;           // 2,097,152

    prep_kernel<<<2560, 256, 0, stream>>>(w_kx, w_qx, proj_w, wkT, wqT, weffb);

    projx_mfma<<<dim3(32, 32), 256, 0, stream>>>(k, q, wkT, wqT, kxh, qxh, kxT);

    fused_attn<<<dim3(64, 16), 256, 0, stream>>>(qxh, kxh, kxT, weffb, proj_b,
                                                 mlen, attn0, out0, use_ws);

    if (!use_ws)
        fixup_kernel<<<5120, 256, 0, stream>>>((const uint4*)attn0,
                                               (uint4*)(attn0 + 2 * BLK));
}